// Round 24
// baseline (125.822 us; speedup 1.0000x reference)
//
#include <hip/hip_runtime.h>

#define BB   1024
#define TT   512
#define NIN  28
#define NS   4
#define MM   7
#define WW   457          // TT - 28 - 28 + 1
#define SLEN 519
#define EMB  9

#define OUT1_SZ (WW * BB * 144)
#define OUT2_SZ (WW * BB * 28)
#define OUT3_SZ (BB * TT)
#define OUT4_SZ (BB * SLEN)

#define CH   32
#define NCH  (TT / CH)
#define NF1  (WW * BB * 36)
#define NF2  (WW * BB * 7)

typedef float f4 __attribute__((ext_vector_type(4)));

__device__ __forceinline__ f4 ld4u(const float* p) {
    f4 v;
    __builtin_memcpy(&v, p, sizeof(f4));
    return v;
}

// ---------------------------------------------------------------------------
// Kernel 1: ES scan (R4 version, proven ~10 us, runs alone).
// ---------------------------------------------------------------------------
__global__ __launch_bounds__(64) void es_scan(const float* __restrict__ Y,
        const int* __restrict__ idxs, const float* __restrict__ EW,
        float* __restrict__ levels, float* __restrict__ seas) {
    __shared__ float yl[64][CH + 1];
    __shared__ float se[64][CH + 1];
    const int tid = threadIdx.x;
    const int b0  = blockIdx.x << 6;
    const int b   = b0 + tid;

    const float* e = EW + idxs[b] * EMB;
    const float lev_sms  = 1.0f / (1.0f + __expf(-e[0]));
    const float seas_sms = 1.0f / (1.0f + __expf(-e[1]));
    const float a_l = 1.0f - lev_sms;
    const float a_s = 1.0f - seas_sms;

    float buf[MM];
    const float is0 = __expf(e[2]);
    {
        float* srow = seas + b * SLEN;
        srow[0] = is0;
#pragma unroll
        for (int k = 1; k < MM; ++k) {
            float v = __expf(e[2 + k]);
            srow[k] = v;
            buf[k - 1] = v;
        }
        buf[MM - 1] = is0;
    }

    f4 pf[8];
#pragma unroll
    for (int k = 0; k < 8; ++k) {
        int flat = (k << 6) + tid;
        int r = flat >> 3, q = flat & 7;
        pf[k] = *reinterpret_cast<const f4*>(Y + (b0 + r) * TT + (q << 2));
    }

    float lev = 0.0f;

#define ES_STEP(TTI)                                                        \
    {                                                                       \
        float y  = yreg[TTI];                                               \
        float st = buf[0];                                                  \
        lev = lev_sms * __fdividef(y, st) + a_l * lev;                      \
        float ns = seas_sms * __fdividef(y, lev) + a_s * st;                \
        buf[0] = buf[1]; buf[1] = buf[2]; buf[2] = buf[3];                  \
        buf[3] = buf[4]; buf[4] = buf[5]; buf[5] = buf[6];                  \
        buf[6] = ns;                                                        \
        yl[tid][TTI] = lev;                                                 \
        se[tid][TTI] = ns;                                                  \
    }

    for (int c = 0; c < NCH; ++c) {
        __syncthreads();
#pragma unroll
        for (int k = 0; k < 8; ++k) {
            int flat = (k << 6) + tid;
            int r = flat >> 3, q = flat & 7;
            float* dst = &yl[r][q << 2];
            dst[0] = pf[k].x; dst[1] = pf[k].y; dst[2] = pf[k].z; dst[3] = pf[k].w;
        }
        __syncthreads();
        if (c < NCH - 1) {
#pragma unroll
            for (int k = 0; k < 8; ++k) {
                int flat = (k << 6) + tid;
                int r = flat >> 3, q = flat & 7;
                pf[k] = *reinterpret_cast<const f4*>(
                    Y + (b0 + r) * TT + (c + 1) * CH + (q << 2));
            }
        }

        float yreg[CH];
#pragma unroll
        for (int tt = 0; tt < CH; ++tt) yreg[tt] = yl[tid][tt];

        if (c == 0) {
            lev = __fdividef(yreg[0], is0);
            yl[tid][0] = lev;
            se[tid][0] = is0;
#pragma unroll
            for (int tt = 1; tt < CH; ++tt) ES_STEP(tt)
        } else {
#pragma unroll
            for (int tt = 0; tt < CH; ++tt) ES_STEP(tt)
        }
        __syncthreads();

#pragma unroll
        for (int k = 0; k < CH; ++k) {
            int flat = (k << 6) + tid;
            int r    = flat >> 5;
            int col  = flat & 31;
            levels[(b0 + r) * TT   + c * CH + col]      = yl[r][col];
            seas  [(b0 + r) * SLEN + MM + c * CH + col] = se[r][col];
        }
    }
#undef ES_STEP
}

// ---------------------------------------------------------------------------
// Kernel 2 (fused): blocks 0..511 = k_pre (LL/LYS into d_ws);
// blocks 512..2559 = out2/out5 streaming. (R23, proven)
// ---------------------------------------------------------------------------
__global__ __launch_bounds__(256) void k_pre_out25(const float* __restrict__ levels,
        const float* __restrict__ seas, const float* __restrict__ Y,
        const float* __restrict__ mask, float* __restrict__ LL,
        float* __restrict__ LYS, f4* __restrict__ out2, f4* __restrict__ out5) {
    const int tid = threadIdx.x;
    if (blockIdx.x < 512) {
        int u  = blockIdx.x * 256 + tid;            // f4 index < 131072
        int b  = u >> 7;
        int t4 = (u & 127) << 2;
        f4 lv = *reinterpret_cast<const f4*>(levels + b * TT + t4);
        f4 yv = *reinterpret_cast<const f4*>(Y      + b * TT + t4);
        f4 sv = ld4u(seas + b * SLEN + t4);
        f4 a, c;
        a.x = __logf(lv.x); a.y = __logf(lv.y);
        a.z = __logf(lv.z); a.w = __logf(lv.w);
        c.x = __logf(yv.x) - __logf(sv.x);
        c.y = __logf(yv.y) - __logf(sv.y);
        c.z = __logf(yv.z) - __logf(sv.z);
        c.w = __logf(yv.w) - __logf(sv.w);
        *reinterpret_cast<f4*>(LL  + b * TT + t4) = a;
        *reinterpret_cast<f4*>(LYS + b * TT + t4) = c;
    } else {
        const int id = blockIdx.x - 512;            // 0..2047
        for (int i = (id << 8) + tid; i < NF2; i += 2048 * 256) {
            int wb = i / 7;
            int j  = i - wb * 7;
            int b  = wb & (BB - 1);
            int w  = wb >> 10;
            int base = w + NIN + (j << 2);
            f4 vy = ld4u(Y    + b * TT + base);
            f4 vm = ld4u(mask + b * TT + base);
            __builtin_nontemporal_store(vy, &out2[i]);
            __builtin_nontemporal_store(vm, &out5[i]);
        }
    }
}

// ---------------------------------------------------------------------------
// Kernel 3: out1 flat + EXPLICIT 4-WAY LOAD BATCHING (MLP 2 -> 4-8).
// All 4 loads issued before any store; divergent class branch per slot
// (proven cheap); uniform 4-sub epilogue. Main loop = 7 uniform iters,
// tail = plain grid-stride.
// ---------------------------------------------------------------------------
#define LOADB(I, A, L)                                                      \
    {                                                                       \
        int wb  = (I) / 36;                                                 \
        int col = (I) - wb * 36;                                            \
        int b   = wb & (BB - 1);                                            \
        int w   = wb >> 10;                                                 \
        if (col < 7) {                                                      \
            A = ld4u(LYS + b * TT + w + (col << 2));                        \
            L = LL[b * TT + w + 27];                                        \
        } else if (col < 35) {                                              \
            int ch = (col >= 21) ? 1 : 0;                                   \
            A = ld4u(X + (size_t)(b * 2 + ch) * TT + w                      \
                     + ((col - 7 - 14 * ch) << 2));                         \
            L = 0.0f;                                                       \
        } else {                                                            \
            A = *reinterpret_cast<const f4*>(S + (b << 2));                 \
            L = 0.0f;                                                       \
        }                                                                   \
    }

__global__ __launch_bounds__(256) void k_out1_mlp(const float* __restrict__ LL,
        const float* __restrict__ LYS, const float* __restrict__ X,
        const float* __restrict__ S, f4* __restrict__ out1) {
    const int stride = gridDim.x * blockDim.x;          // 524288
    int i = blockIdx.x * blockDim.x + threadIdx.x;

    for (; i + 3 * stride < NF1; i += 4 * stride) {
        f4 a0, a1, a2, a3;
        float l0, l1, l2, l3;
        LOADB(i,              a0, l0)
        LOADB(i +     stride, a1, l1)
        LOADB(i + 2 * stride, a2, l2)
        LOADB(i + 3 * stride, a3, l3)
        f4 v0, v1, v2, v3;
        v0.x = a0.x - l0; v0.y = a0.y - l0; v0.z = a0.z - l0; v0.w = a0.w - l0;
        v1.x = a1.x - l1; v1.y = a1.y - l1; v1.z = a1.z - l1; v1.w = a1.w - l1;
        v2.x = a2.x - l2; v2.y = a2.y - l2; v2.z = a2.z - l2; v2.w = a2.w - l2;
        v3.x = a3.x - l3; v3.y = a3.y - l3; v3.z = a3.z - l3; v3.w = a3.w - l3;
        __builtin_nontemporal_store(v0, &out1[i]);
        __builtin_nontemporal_store(v1, &out1[i +     stride]);
        __builtin_nontemporal_store(v2, &out1[i + 2 * stride]);
        __builtin_nontemporal_store(v3, &out1[i + 3 * stride]);
    }
    for (; i < NF1; i += stride) {
        f4 a; float l;
        LOADB(i, a, l)
        f4 v;
        v.x = a.x - l; v.y = a.y - l; v.z = a.z - l; v.w = a.w - l;
        __builtin_nontemporal_store(v, &out1[i]);
    }
}
#undef LOADB

// ---------------------------------------------------------------------------
// Fallback kernels (ws too small): R21 divergent flat w/ inline logs + out25.
// ---------------------------------------------------------------------------
__global__ __launch_bounds__(256) void k_out1_flat0(const float* __restrict__ levels,
        const float* __restrict__ seas, const float* __restrict__ Yg,
        const float* __restrict__ X, const float* __restrict__ S,
        f4* __restrict__ out1) {
    int i = blockIdx.x * blockDim.x + threadIdx.x;
    const int stride = gridDim.x * blockDim.x;
    for (; i < NF1; i += stride) {
        int wb  = i / 36;
        int col = i - wb * 36;
        int b   = wb & (BB - 1);
        int w   = wb >> 10;
        f4 v;
        if (col < 7) {
            int t = w + (col << 2);
            f4 yv = ld4u(Yg + b * TT + t);
            f4 sv = ld4u(seas + b * SLEN + t);
            float le = levels[b * TT + w + 27];
            v.x = __logf(__fdividef(yv.x, le * sv.x));
            v.y = __logf(__fdividef(yv.y, le * sv.y));
            v.z = __logf(__fdividef(yv.z, le * sv.z));
            v.w = __logf(__fdividef(yv.w, le * sv.w));
        } else if (col < 35) {
            int ch = (col >= 21) ? 1 : 0;
            v = ld4u(X + (size_t)(b * 2 + ch) * TT + w + ((col - 7 - 14 * ch) << 2));
        } else {
            v = *reinterpret_cast<const f4*>(S + (b << 2));
        }
        __builtin_nontemporal_store(v, &out1[i]);
    }
}

__global__ __launch_bounds__(256) void k_out25(const float* __restrict__ Y,
        const float* __restrict__ mask, f4* __restrict__ out2,
        f4* __restrict__ out5) {
    int i = blockIdx.x * blockDim.x + threadIdx.x;
    const int stride = gridDim.x * blockDim.x;
    for (; i < NF2; i += stride) {
        int wb = i / 7;
        int j  = i - wb * 7;
        int b  = wb & (BB - 1);
        int w  = wb >> 10;
        int base = w + NIN + (j << 2);
        f4 vy = ld4u(Y    + b * TT + base);
        f4 vm = ld4u(mask + b * TT + base);
        __builtin_nontemporal_store(vy, &out2[i]);
        __builtin_nontemporal_store(vm, &out5[i]);
    }
}

extern "C" void kernel_launch(void* const* d_in, const int* in_sizes, int n_in,
                              void* d_out, int out_size, void* d_ws, size_t ws_size,
                              hipStream_t stream) {
    const float* S    = (const float*)d_in[0];
    const float* Y    = (const float*)d_in[1];
    const float* X    = (const float*)d_in[2];
    const int*   idxs = (const int*)d_in[3];
    const float* mask = (const float*)d_in[4];
    const float* EW   = (const float*)d_in[5];

    float* out  = (float*)d_out;
    float* out1 = out;
    float* out2 = out1 + OUT1_SZ;
    float* out3 = out2 + OUT2_SZ;        // levels
    float* out4 = out3 + OUT3_SZ;        // seasonalities
    float* out5 = out4 + OUT4_SZ;        // mask_w

    es_scan<<<16, 64, 0, stream>>>(Y, idxs, EW, out3, out4);

    const size_t need = (size_t)2 * BB * TT * sizeof(float);   // 4 MB
    if (ws_size >= need) {
        float* LL  = (float*)d_ws;
        float* LYS = LL + BB * TT;
        k_pre_out25<<<2560, 256, 0, stream>>>(out3, out4, Y, mask, LL, LYS,
                                              (f4*)out2, (f4*)out5);
        k_out1_mlp<<<2048, 256, 0, stream>>>(LL, LYS, X, S, (f4*)out1);
    } else {
        k_out1_flat0<<<2048, 256, 0, stream>>>(out3, out4, Y, X, S, (f4*)out1);
        k_out25<<<2048, 256, 0, stream>>>(Y, mask, (f4*)out2, (f4*)out5);
    }
}

// Round 25
// 114.449 us; speedup vs baseline: 1.0994x; 1.0994x over previous
//
#include <hip/hip_runtime.h>

#define BB   1024
#define TT   512
#define NIN  28
#define NS   4
#define MM   7
#define WW   457          // TT - 28 - 28 + 1
#define SLEN 519
#define EMB  9

#define OUT1_SZ (WW * BB * 144)
#define OUT2_SZ (WW * BB * 28)
#define OUT3_SZ (BB * TT)
#define OUT4_SZ (BB * SLEN)

#define CH   32
#define NCH  (TT / CH)
#define NF1  (WW * BB * 36)
#define NF2  (WW * BB * 7)

typedef float f4 __attribute__((ext_vector_type(4)));

__device__ __forceinline__ f4 ld4u(const float* p) {
    f4 v;
    __builtin_memcpy(&v, p, sizeof(f4));
    return v;
}

// ---------------------------------------------------------------------------
// Kernel 1: ES scan (R4 version, proven ~10 us, runs alone).
// ---------------------------------------------------------------------------
__global__ __launch_bounds__(64) void es_scan(const float* __restrict__ Y,
        const int* __restrict__ idxs, const float* __restrict__ EW,
        float* __restrict__ levels, float* __restrict__ seas) {
    __shared__ float yl[64][CH + 1];
    __shared__ float se[64][CH + 1];
    const int tid = threadIdx.x;
    const int b0  = blockIdx.x << 6;
    const int b   = b0 + tid;

    const float* e = EW + idxs[b] * EMB;
    const float lev_sms  = 1.0f / (1.0f + __expf(-e[0]));
    const float seas_sms = 1.0f / (1.0f + __expf(-e[1]));
    const float a_l = 1.0f - lev_sms;
    const float a_s = 1.0f - seas_sms;

    float buf[MM];
    const float is0 = __expf(e[2]);
    {
        float* srow = seas + b * SLEN;
        srow[0] = is0;
#pragma unroll
        for (int k = 1; k < MM; ++k) {
            float v = __expf(e[2 + k]);
            srow[k] = v;
            buf[k - 1] = v;
        }
        buf[MM - 1] = is0;
    }

    f4 pf[8];
#pragma unroll
    for (int k = 0; k < 8; ++k) {
        int flat = (k << 6) + tid;
        int r = flat >> 3, q = flat & 7;
        pf[k] = *reinterpret_cast<const f4*>(Y + (b0 + r) * TT + (q << 2));
    }

    float lev = 0.0f;

#define ES_STEP(TTI)                                                        \
    {                                                                       \
        float y  = yreg[TTI];                                               \
        float st = buf[0];                                                  \
        lev = lev_sms * __fdividef(y, st) + a_l * lev;                      \
        float ns = seas_sms * __fdividef(y, lev) + a_s * st;                \
        buf[0] = buf[1]; buf[1] = buf[2]; buf[2] = buf[3];                  \
        buf[3] = buf[4]; buf[4] = buf[5]; buf[5] = buf[6];                  \
        buf[6] = ns;                                                        \
        yl[tid][TTI] = lev;                                                 \
        se[tid][TTI] = ns;                                                  \
    }

    for (int c = 0; c < NCH; ++c) {
        __syncthreads();
#pragma unroll
        for (int k = 0; k < 8; ++k) {
            int flat = (k << 6) + tid;
            int r = flat >> 3, q = flat & 7;
            float* dst = &yl[r][q << 2];
            dst[0] = pf[k].x; dst[1] = pf[k].y; dst[2] = pf[k].z; dst[3] = pf[k].w;
        }
        __syncthreads();
        if (c < NCH - 1) {
#pragma unroll
            for (int k = 0; k < 8; ++k) {
                int flat = (k << 6) + tid;
                int r = flat >> 3, q = flat & 7;
                pf[k] = *reinterpret_cast<const f4*>(
                    Y + (b0 + r) * TT + (c + 1) * CH + (q << 2));
            }
        }

        float yreg[CH];
#pragma unroll
        for (int tt = 0; tt < CH; ++tt) yreg[tt] = yl[tid][tt];

        if (c == 0) {
            lev = __fdividef(yreg[0], is0);
            yl[tid][0] = lev;
            se[tid][0] = is0;
#pragma unroll
            for (int tt = 1; tt < CH; ++tt) ES_STEP(tt)
        } else {
#pragma unroll
            for (int tt = 0; tt < CH; ++tt) ES_STEP(tt)
        }
        __syncthreads();

#pragma unroll
        for (int k = 0; k < CH; ++k) {
            int flat = (k << 6) + tid;
            int r    = flat >> 5;
            int col  = flat & 31;
            levels[(b0 + r) * TT   + c * CH + col]      = yl[r][col];
            seas  [(b0 + r) * SLEN + MM + c * CH + col] = se[r][col];
        }
    }
#undef ES_STEP
}

// ---------------------------------------------------------------------------
// Kernel 2 (fused): blocks 0..511 = k_pre (LL/LYS into d_ws);
// blocks 512..2559 = out2/out5 streaming. (R23, proven)
// ---------------------------------------------------------------------------
__global__ __launch_bounds__(256) void k_pre_out25(const float* __restrict__ levels,
        const float* __restrict__ seas, const float* __restrict__ Y,
        const float* __restrict__ mask, float* __restrict__ LL,
        float* __restrict__ LYS, f4* __restrict__ out2, f4* __restrict__ out5) {
    const int tid = threadIdx.x;
    if (blockIdx.x < 512) {
        // ---------------- k_pre ----------------
        int u  = blockIdx.x * 256 + tid;            // f4 index < 131072
        int b  = u >> 7;
        int t4 = (u & 127) << 2;
        f4 lv = *reinterpret_cast<const f4*>(levels + b * TT + t4);
        f4 yv = *reinterpret_cast<const f4*>(Y      + b * TT + t4);
        f4 sv = ld4u(seas + b * SLEN + t4);
        f4 a, c;
        a.x = __logf(lv.x); a.y = __logf(lv.y);
        a.z = __logf(lv.z); a.w = __logf(lv.w);
        c.x = __logf(yv.x) - __logf(sv.x);
        c.y = __logf(yv.y) - __logf(sv.y);
        c.z = __logf(yv.z) - __logf(sv.z);
        c.w = __logf(yv.w) - __logf(sv.w);
        *reinterpret_cast<f4*>(LL  + b * TT + t4) = a;
        *reinterpret_cast<f4*>(LYS + b * TT + t4) = c;
    } else {
        // ---------------- out2 + out5 ----------------
        const int id = blockIdx.x - 512;            // 0..2047
        for (int i = (id << 8) + tid; i < NF2; i += 2048 * 256) {
            int wb = i / 7;
            int j  = i - wb * 7;
            int b  = wb & (BB - 1);
            int w  = wb >> 10;
            int base = w + NIN + (j << 2);
            f4 vy = ld4u(Y    + b * TT + base);
            f4 vm = ld4u(mask + b * TT + base);
            __builtin_nontemporal_store(vy, &out2[i]);
            __builtin_nontemporal_store(vm, &out5[i]);
        }
    }
}

// ---------------------------------------------------------------------------
// Kernel 3: out1 flat (R21 recipe) + unroll-2. (R23, proven best: ~68us)
// PRE=1: logs from d_ws; PRE=0 fallback inline.
// ---------------------------------------------------------------------------
template<int PRE>
__global__ __launch_bounds__(256) void k_out1_flat(const float* __restrict__ P1,
        const float* __restrict__ P2, const float* __restrict__ Yg,
        const float* __restrict__ X, const float* __restrict__ S,
        f4* __restrict__ out1) {
    int i = blockIdx.x * blockDim.x + threadIdx.x;
    const int stride = gridDim.x * blockDim.x;
#pragma unroll 2
    for (; i < NF1; i += stride) {
        int wb  = i / 36;
        int col = i - wb * 36;
        int b   = wb & (BB - 1);
        int w   = wb >> 10;
        f4 v;
        if (col < 7) {
            if (PRE) {
                v = ld4u(P2 + b * TT + w + (col << 2));     // LYS
                float l = P1[b * TT + w + 27];               // LL
                v.x -= l; v.y -= l; v.z -= l; v.w -= l;
            } else {
                int t = w + (col << 2);
                f4 yv = ld4u(Yg + b * TT + t);
                f4 sv = ld4u(P2 + b * SLEN + t);
                float le = P1[b * TT + w + 27];
                v.x = __logf(__fdividef(yv.x, le * sv.x));
                v.y = __logf(__fdividef(yv.y, le * sv.y));
                v.z = __logf(__fdividef(yv.z, le * sv.z));
                v.w = __logf(__fdividef(yv.w, le * sv.w));
            }
        } else if (col < 35) {
            int ch = (col >= 21) ? 1 : 0;
            v = ld4u(X + (size_t)(b * 2 + ch) * TT + w + ((col - 7 - 14 * ch) << 2));
        } else {
            v = *reinterpret_cast<const f4*>(S + (b << 2));
        }
        __builtin_nontemporal_store(v, &out1[i]);
    }
}

// ---------------------------------------------------------------------------
// Kernel 4 (fallback path only): out2 + out5 standalone.
// ---------------------------------------------------------------------------
__global__ __launch_bounds__(256) void k_out25(const float* __restrict__ Y,
        const float* __restrict__ mask, f4* __restrict__ out2,
        f4* __restrict__ out5) {
    int i = blockIdx.x * blockDim.x + threadIdx.x;
    const int stride = gridDim.x * blockDim.x;
    for (; i < NF2; i += stride) {
        int wb = i / 7;
        int j  = i - wb * 7;
        int b  = wb & (BB - 1);
        int w  = wb >> 10;
        int base = w + NIN + (j << 2);
        f4 vy = ld4u(Y    + b * TT + base);
        f4 vm = ld4u(mask + b * TT + base);
        __builtin_nontemporal_store(vy, &out2[i]);
        __builtin_nontemporal_store(vm, &out5[i]);
    }
}

extern "C" void kernel_launch(void* const* d_in, const int* in_sizes, int n_in,
                              void* d_out, int out_size, void* d_ws, size_t ws_size,
                              hipStream_t stream) {
    const float* S    = (const float*)d_in[0];
    const float* Y    = (const float*)d_in[1];
    const float* X    = (const float*)d_in[2];
    const int*   idxs = (const int*)d_in[3];
    const float* mask = (const float*)d_in[4];
    const float* EW   = (const float*)d_in[5];

    float* out  = (float*)d_out;
    float* out1 = out;
    float* out2 = out1 + OUT1_SZ;
    float* out3 = out2 + OUT2_SZ;        // levels
    float* out4 = out3 + OUT3_SZ;        // seasonalities
    float* out5 = out4 + OUT4_SZ;        // mask_w

    es_scan<<<16, 64, 0, stream>>>(Y, idxs, EW, out3, out4);

    const size_t need = (size_t)2 * BB * TT * sizeof(float);   // 4 MB
    if (ws_size >= need) {
        float* LL  = (float*)d_ws;
        float* LYS = LL + BB * TT;
        k_pre_out25<<<2560, 256, 0, stream>>>(out3, out4, Y, mask, LL, LYS,
                                              (f4*)out2, (f4*)out5);
        k_out1_flat<1><<<2048, 256, 0, stream>>>(LL, LYS, Y, X, S, (f4*)out1);
    } else {
        k_out1_flat<0><<<2048, 256, 0, stream>>>(out3, out4, Y, X, S, (f4*)out1);
        k_out25<<<2048, 256, 0, stream>>>(Y, mask, (f4*)out2, (f4*)out5);
    }
}